// Round 19
// baseline (504.365 us; speedup 1.0000x reference)
//
#include <hip/hip_runtime.h>
#include <hip/hip_bf16.h>

// ---------------------------------------------------------------------------
// Transformer block. Token rows permuted to r' = b*2048+s after LN1.
// 256x256 8-phase deep-pipelined bf16 MFMA GEMMs + bf16 32x32 swapped-QK^T
// flash attn: 8-wave (512-thr) blocks share one staged K/V tile (LDS 40KB
// amortized over 2x waves -> 24 waves/CU), K 3-buf / V 2-buf, counted-vmcnt
// barriers (vmcnt(1): 1-load stages). Max-free softmax, ones-row norm,
// K-dim 48, stack-split. QKV GEMM grid z-adjacent for A-panel L2 reuse.
// Heads: 8 x 43 + 4 x 42, padded to 64 dims for MFMA.
// ---------------------------------------------------------------------------

#define M_ROWS 32768
#define DM 512
#define SEQ 2048
#define BATCH 16
#define SLAB_ELEMS (24u * 1024u * 1024u)   // 48MB / 2B per QKV slab

typedef __bf16 bf16x8 __attribute__((ext_vector_type(8)));
typedef float f32x4 __attribute__((ext_vector_type(4)));
typedef float f32x16 __attribute__((ext_vector_type(16)));

#define EXP2F(x) __builtin_amdgcn_exp2f(x)

typedef __attribute__((address_space(3))) unsigned lds_u32;
typedef __attribute__((address_space(1))) unsigned glb_u32;
#define GL2LDS(src, dst) __builtin_amdgcn_global_load_lds( \
    (const glb_u32*)(const void*)(src), (lds_u32*)(void*)(dst), 16, 0, 0)

#define BARRIER_VM4() asm volatile("s_waitcnt vmcnt(4)\ns_barrier" ::: "memory")
#define BARRIER_VM1() asm volatile("s_waitcnt vmcnt(1)\ns_barrier" ::: "memory")
#define BARRIER_VM0() asm volatile("s_waitcnt vmcnt(0)\ns_barrier" ::: "memory")
#define BARRIER_ONLY() asm volatile("s_barrier" ::: "memory")

#define MFMA16(a, b, c) __builtin_amdgcn_mfma_f32_16x16x32_bf16(a, b, c, 0, 0, 0)

__device__ inline unsigned pkbf16(float a, float b) {
    unsigned r;
    asm("v_cvt_pk_bf16_f32 %0, %1, %2" : "=v"(r) : "v"(a), "v"(b));
    return r;
}

// ---------------- fused prep: Wt x5 | q pad-zero | v ones | LN1 ------------
__global__ __launch_bounds__(256) void prep_kernel(
    const float* __restrict__ Wq, const float* __restrict__ Wk,
    const float* __restrict__ Wv, const float* __restrict__ Wf1,
    const float* __restrict__ Wf2, __bf16* __restrict__ Wts,
    __bf16* __restrict__ q, __bf16* __restrict__ v,
    const float* __restrict__ x, const float* __restrict__ g1,
    const float* __restrict__ b1, __bf16* __restrict__ normed)
{
    int blk = blockIdx.x;
    if (blk < 5120) {
        int g = blk >> 10;
        int idx = (blk & 1023) * 256 + threadIdx.x;
        const float* W = (g == 0) ? Wq : (g == 1) ? Wk : (g == 2) ? Wv
                        : (g == 3) ? Wf1 : Wf2;
        __bf16* Wt = Wts + (size_t)g * (DM * DM);
        int n = idx >> 9, k = idx & 511;
        Wt[idx] = (__bf16)W[k * DM + n];
    } else if (blk < 6656) {
        int row = (blk - 5120) * 256 + threadIdx.x;   // 0..393215
        union { __bf16 h[8]; bf16x8 v8; } z;
#pragma unroll
        for (int j = 0; j < 8; ++j) z.h[j] = (__bf16)0.f;
        *(bf16x8*)(q + (size_t)row * 64 + 40) = z.v8;
    } else if (blk < 6848) {
        int i = (blk - 6656) * 256 + threadIdx.x;     // 0..49151
        int bh = i >> 8, s8 = i & 255;
        int hd = ((bh % 12) < 8) ? 43 : 42;
        union { __bf16 h[8]; bf16x8 v8; } o;
#pragma unroll
        for (int j = 0; j < 8; ++j) o.h[j] = (__bf16)1.0f;
        *(bf16x8*)(v + ((size_t)bh * 64 + hd) * SEQ + s8 * 8) = o.v8;
    } else {
        int wid  = (int)(((blk - 6848) * 256 + threadIdx.x) >> 6);   // r'
        int lane = threadIdx.x & 63;
        int bb = wid >> 11, ss = wid & 2047;
        const float* xrow = x + ((size_t)ss * 16 + bb) * DM;
        float vv[8];
        *(float4*)&vv[0] = *(const float4*)(xrow + lane * 8);
        *(float4*)&vv[4] = *(const float4*)(xrow + lane * 8 + 4);
        float s = 0.f, sq = 0.f;
#pragma unroll
        for (int j = 0; j < 8; ++j) { s += vv[j]; sq = fmaf(vv[j], vv[j], sq); }
#pragma unroll
        for (int i = 1; i < 64; i <<= 1) { s += __shfl_xor(s, i); sq += __shfl_xor(sq, i); }
        float mu   = s * (1.0f / 512.0f);
        float var  = sq * (1.0f / 512.0f) - mu * mu;
        float rstd = rsqrtf(var + 1e-5f);
        union { __bf16 h[8]; bf16x8 v8; } o;
#pragma unroll
        for (int j = 0; j < 8; ++j)
            o.h[j] = (__bf16)((vv[j] - mu) * rstd * g1[lane * 8 + j] + b1[lane * 8 + j]);
        *(bf16x8*)(normed + (size_t)wid * DM + lane * 8) = o.v8;
    }
}

// ---------------- LN2: attnc (r') + x resid (r) -> bf16 out (r') -----------
__global__ __launch_bounds__(256) void ln2_kernel(
    const __bf16* __restrict__ in, const float* __restrict__ res,
    const float* __restrict__ g, const float* __restrict__ b,
    __bf16* __restrict__ outb)
{
    int wid  = (int)((blockIdx.x * 256 + threadIdx.x) >> 6);   // r'
    int lane = threadIdx.x & 63;
    int bb = wid >> 11, ss = wid & 2047;
    union { __bf16 h[8]; bf16x8 v8; } iv;
    iv.v8 = *(const bf16x8*)(in + (size_t)wid * DM + lane * 8);
    const float* rrow = res + ((size_t)ss * 16 + bb) * DM;
    float v[8];
    float4 r0 = *(const float4*)(rrow + lane * 8);
    float4 r1 = *(const float4*)(rrow + lane * 8 + 4);
    v[0] = (float)iv.h[0] + r0.x; v[1] = (float)iv.h[1] + r0.y;
    v[2] = (float)iv.h[2] + r0.z; v[3] = (float)iv.h[3] + r0.w;
    v[4] = (float)iv.h[4] + r1.x; v[5] = (float)iv.h[5] + r1.y;
    v[6] = (float)iv.h[6] + r1.z; v[7] = (float)iv.h[7] + r1.w;
    float s = 0.f, sq = 0.f;
#pragma unroll
    for (int j = 0; j < 8; ++j) { s += v[j]; sq = fmaf(v[j], v[j], sq); }
#pragma unroll
    for (int i = 1; i < 64; i <<= 1) { s += __shfl_xor(s, i); sq += __shfl_xor(sq, i); }
    float mu   = s * (1.0f / 512.0f);
    float var  = sq * (1.0f / 512.0f) - mu * mu;
    float rstd = rsqrtf(var + 1e-5f);
    union { __bf16 h[8]; bf16x8 v8; } ob;
#pragma unroll
    for (int j = 0; j < 8; ++j)
        ob.h[j] = (__bf16)((v[j] - mu) * rstd * g[lane * 8 + j] + b[lane * 8 + j]);
    *(bf16x8*)(outb + (size_t)wid * DM + lane * 8) = ob.v8;
}

// ---------------- 256x256 8-phase bf16 MFMA GEMM ---------------------------
// mode -1: fused QKV, grid (6,128): x = z*2+n so all 6 blocks sharing an
// A-panel are adjacent (A read once from HBM, L2-hit for the other 5).
__global__ __launch_bounds__(512, 2) void gemm256_kernel(
    const __bf16* __restrict__ A, const __bf16* __restrict__ Wt,
    const float* __restrict__ bias, const __bf16* __restrict__ residb,
    void* __restrict__ Cout, int mode, int do_relu)
{
    extern __shared__ char lds[];   // 131072 B
    const int tid  = threadIdx.x;
    const int lane = tid & 63, wave = tid >> 6;
    const int wm = wave >> 2, wn = wave & 3;
    const int m0 = blockIdx.y * 256;
    int n0;
    if (mode == -1) {
        int z = blockIdx.x >> 1;
        mode = 1 + z;
        Wt += (size_t)z * DM * DM;
        Cout = (void*)((__bf16*)Cout + (size_t)z * SLAB_ELEMS);
        n0 = (blockIdx.x & 1) * 256;
    } else {
        n0 = blockIdx.x * 256;
    }

    const int c0 = tid >> 4, r0 = tid & 15;
    const int rowoff = (c0 >> 2) * 16 + r0;
    const int kcol   = (c0 & 3) * 8;
    const __bf16* aS0 = A  + (size_t)(m0 + rowoff) * DM + kcol;
    const __bf16* aS1 = aS0 + (size_t)128 * DM;
    const __bf16* bS0 = Wt + (size_t)(n0 + rowoff) * DM + kcol;
    const __bf16* bS1 = bS0 + (size_t)128 * DM;

#define STG(tile, hh, buf) do { \
    const int kk_ = (tile) * 64 + ((hh) >> 1) * 32; \
    char* d_ = lds + (buf) * 65536 + ((hh) & 1) * 32768 + ((hh) >> 1) * 16384 + tid * 16; \
    const __bf16* sA_ = ((hh) & 1) ? bS0 : aS0; \
    const __bf16* sB_ = ((hh) & 1) ? bS1 : aS1; \
    GL2LDS(sA_ + kk_, d_); \
    GL2LDS(sB_ + kk_, d_ + 8192); \
} while (0)

    const int aRd = wm * 8192 + (lane >> 4) * 256 + (lane & 15) * 16;
    const int bRd = 32768 + wn * 4096 + (lane >> 4) * 256 + (lane & 15) * 16;

    f32x4 acc[8][4];
#pragma unroll
    for (int m = 0; m < 8; ++m)
#pragma unroll
        for (int n = 0; n < 4; ++n) acc[m][n] = f32x4{0.f, 0.f, 0.f, 0.f};

    STG(0, 0, 0); STG(0, 1, 0); STG(0, 2, 0); STG(0, 3, 0);
    BARRIER_VM4();

    bf16x8 bq0, bq1, bq2, bq3;

#define DO_PHASE(PH) do { \
    constexpr int buf_ = (PH) >> 2, kh_ = ((PH) >> 1) & 1, qm_ = (PH) & 1; \
    if constexpr ((PH) == 0) { if (it != 0) BARRIER_VM4(); } \
    else if constexpr (((PH) & 1) == 0) { \
        if (it == 3 && (PH) >= 4) BARRIER_VM0(); else BARRIER_VM4(); \
    } \
    char* base_ = lds + buf_ * 65536 + kh_ * 16384; \
    bf16x8 af0 = *(const bf16x8*)(base_ + aRd + (qm_ * 4 + 0) * 1024); \
    bf16x8 af1 = *(const bf16x8*)(base_ + aRd + (qm_ * 4 + 1) * 1024); \
    bf16x8 af2 = *(const bf16x8*)(base_ + aRd + (qm_ * 4 + 2) * 1024); \
    bf16x8 af3 = *(const bf16x8*)(base_ + aRd + (qm_ * 4 + 3) * 1024); \
    if constexpr (qm_ == 0) { \
        bq0 = *(const bf16x8*)(base_ + bRd + 0 * 1024); \
        bq1 = *(const bf16x8*)(base_ + bRd + 1 * 1024); \
        bq2 = *(const bf16x8*)(base_ + bRd + 2 * 1024); \
        bq3 = *(const bf16x8*)(base_ + bRd + 3 * 1024); \
    } \
    if constexpr ((PH) < 4) { STG(2 * it + 1, (PH), 1); } \
    else { if (it < 3) STG(2 * it + 2, (PH) - 4, 0); } \
    __builtin_amdgcn_s_setprio(1); \
    acc[qm_ * 4 + 0][0] = MFMA16(af0, bq0, acc[qm_ * 4 + 0][0]); \
    acc[qm_ * 4 + 0][1] = MFMA16(af0, bq1, acc[qm_ * 4 + 0][1]); \
    acc[qm_ * 4 + 0][2] = MFMA16(af0, bq2, acc[qm_ * 4 + 0][2]); \
    acc[qm_ * 4 + 0][3] = MFMA16(af0, bq3, acc[qm_ * 4 + 0][3]); \
    acc[qm_ * 4 + 1][0] = MFMA16(af1, bq0, acc[qm_ * 4 + 1][0]); \
    acc[qm_ * 4 + 1][1] = MFMA16(af1, bq1, acc[qm_ * 4 + 1][1]); \
    acc[qm_ * 4 + 1][2] = MFMA16(af1, bq2, acc[qm_ * 4 + 1][2]); \
    acc[qm_ * 4 + 1][3] = MFMA16(af1, bq3, acc[qm_ * 4 + 1][3]); \
    acc[qm_ * 4 + 2][0] = MFMA16(af2, bq0, acc[qm_ * 4 + 2][0]); \
    acc[qm_ * 4 + 2][1] = MFMA16(af2, bq1, acc[qm_ * 4 + 2][1]); \
    acc[qm_ * 4 + 2][2] = MFMA16(af2, bq2, acc[qm_ * 4 + 2][2]); \
    acc[qm_ * 4 + 2][3] = MFMA16(af2, bq3, acc[qm_ * 4 + 2][3]); \
    acc[qm_ * 4 + 3][0] = MFMA16(af3, bq0, acc[qm_ * 4 + 3][0]); \
    acc[qm_ * 4 + 3][1] = MFMA16(af3, bq1, acc[qm_ * 4 + 3][1]); \
    acc[qm_ * 4 + 3][2] = MFMA16(af3, bq2, acc[qm_ * 4 + 3][2]); \
    acc[qm_ * 4 + 3][3] = MFMA16(af3, bq3, acc[qm_ * 4 + 3][3]); \
    __builtin_amdgcn_s_setprio(0); \
} while (0)

    for (int it = 0; it < 4; ++it) {
        DO_PHASE(0); DO_PHASE(1); DO_PHASE(2); DO_PHASE(3);
        DO_PHASE(4); DO_PHASE(5); DO_PHASE(6); DO_PHASE(7);
    }
#undef DO_PHASE
#undef STG

#pragma unroll
    for (int m = 0; m < 8; ++m) {
#pragma unroll
        for (int n = 0; n < 4; ++n) {
            int col = n0 + wn * 64 + n * 16 + (lane & 15);
            int h = 0, d = 0;
            float sc = 1.f;
            if (mode >= 1 && mode <= 3) {
                if (col < 344) { h = col / 43; d = col - 43 * h; }
                else { int nn = col - 344; h = 8 + nn / 42; d = nn - 42 * (nn / 42); }
                if (mode == 1) sc = (h < 8) ? 0.22000894f : 0.22261268f;
            }
#pragma unroll
            for (int reg = 0; reg < 4; ++reg) {
                int row = m0 + wm * 128 + m * 16 + (lane >> 4) * 4 + reg;
                int b_ = row >> 11, s_ = row & 2047;
                float vv = acc[m][n][reg];
                if (bias) vv += bias[col];
                if (do_relu) vv = fmaxf(vv, 0.f);
                if (mode == 5) {
                    vv += (float)residb[(size_t)row * DM + col];
                    ((float*)Cout)[((size_t)s_ * 16 + b_) * DM + col] = vv;
                } else if (mode == 4) {
                    ((__bf16*)Cout)[(size_t)row * DM + col] = (__bf16)vv;
                } else {
                    if (mode == 1)
                        ((__bf16*)Cout)[(((size_t)b_ * 12 + h) * SEQ + s_) * 64 + d] = (__bf16)(vv * sc);
                    else if (mode == 2)
                        ((__bf16*)Cout)[(((size_t)b_ * 12 + h) * SEQ + s_) * 64 + d] = (__bf16)vv;
                    else
                        ((__bf16*)Cout)[(((size_t)b_ * 12 + h) * 64 + d) * SEQ + s_] = (__bf16)vv;
                }
            }
        }
    }
}

// ---------------- MFMA flash attention: 8-wave blocks, staged K/V ----------
// 512 threads = 8 waves x 32 queries = 256 queries/block; one staged 8KB K/V
// tile shared by all 8 waves (2x wave/LDS vs R14). 1-load stages: vmcnt(1).
__global__ __launch_bounds__(512, 5) void attn_mfma_kernel(
    const __bf16* __restrict__ q, const __bf16* __restrict__ k,
    const __bf16* __restrict__ v, __bf16* __restrict__ attnc)
{
    __shared__ union {
        struct { __bf16 K[3][4096]; __bf16 V[2][4096]; } s;   // 40 KB
        float Olds[8][32][33];                                 // 33.8 KB
    } sm;
    char* smb = (char*)&sm;

    const int tid  = threadIdx.x;
    const int wave = tid >> 6, lane = tid & 63;
    const int ln = lane & 31, hi = lane >> 5;

    // 1536 blocks; XCD swizzle: 192 consecutive sw per XCD; qc fastest.
    int sw = (blockIdx.x & 7) * 192 + (blockIdx.x >> 3);
    int qc = sw & 7;                 // 8 chunks of 256 queries
    int h  = (sw >> 3) % 12;
    int b  = sw / 96;
    int hd  = (h < 8) ? 43 : 42;
    int off = (h < 8) ? 43 * h : 42 * h + 8;

    const __bf16* Qbh = q + ((size_t)b * 12 + h) * SEQ * 64;
    const char* Kbase = (const char*)(k + ((size_t)b * 12 + h) * SEQ * 64);
    const char* Vbase = (const char*)(v + ((size_t)b * 12 + h) * 64 * SEQ);

    int q0 = qc * 256 + wave * 32;

    bf16x8 qf[3];   // k-steps 0..2 only (d 0..47; q pads zeroed by prep)
#pragma unroll
    for (int ks = 0; ks < 3; ++ks)
        qf[ks] = *(const bf16x8*)(Qbh + (size_t)(q0 + ln) * 64 + ks * 16 + hi * 8);

    const int rc = tid >> 3;                 // tile row 0..63
    const int ob = (tid & 7) << 4;           // 16B offset in 128B row
    const int sb = ob ^ ((rc & 7) << 4);     // swizzled source byte

#define STAGE_K(t, buf) \
    GL2LDS(Kbase + (size_t)(t) * 8192 + rc * 128 + sb, smb + (buf) * 8192 + tid * 16)
#define STAGE_V(t, buf) \
    GL2LDS(Vbase + (size_t)rc * 4096 + (t) * 128 + sb, smb + 24576 + (buf) * 8192 + tid * 16)

    f32x16 oT0, oT1, z16;
#pragma unroll
    for (int i = 0; i < 16; ++i) { oT0[i] = 0.f; oT1[i] = 0.f; z16[i] = 0.f; }

    const int swr = (ln & 7) << 4;

    STAGE_K(0, 0);
    STAGE_V(0, 0);
    STAGE_K(1, 1);
    BARRIER_VM1();   // K0,V0 resident; K1 in flight

#define DO_STACK(KROW, KSA0) do { \
    f32x16 s_; \
    __builtin_amdgcn_s_setprio(1); \
    { \
        int cb = (hi * 16) ^ swr; \
        bf16x8 ka = *(const bf16x8*)(Kc + (size_t)((KROW) + ln) * 64 + (cb >> 1)); \
        s_ = __builtin_amdgcn_mfma_f32_32x32x16_bf16(ka, qf[0], z16, 0, 0, 0); \
    } \
    { \
        int cb = (32 + hi * 16) ^ swr; \
        bf16x8 ka = *(const bf16x8*)(Kc + (size_t)((KROW) + ln) * 64 + (cb >> 1)); \
        s_ = __builtin_amdgcn_mfma_f32_32x32x16_bf16(ka, qf[1], s_, 0, 0, 0); \
    } \
    { \
        int cb = (64 + hi * 16) ^ swr; \
        bf16x8 ka = *(const bf16x8*)(Kc + (size_t)((KROW) + ln) * 64 + (cb >> 1)); \
        s_ = __builtin_amdgcn_mfma_f32_32x32x16_bf16(ka, qf[2], s_, 0, 0, 0); \
    } \
    __builtin_amdgcn_s_setprio(0); \
    _Pragma("unroll") \
    for (int i = 0; i < 16; ++i) s_[i] = EXP2F(s_[i]); \
    _Pragma("unroll") \
    for (int h16 = 0; h16 < 2; ++h16) { \
        const int pb = h16 * 8; \
        unsigned a0 = pkbf16(s_[pb + 0], s_[pb + 1]); \
        unsigned b0 = pkbf16(s_[pb + 4], s_[pb + 5]); \
        unsigned a1 = pkbf16(s_[pb + 2], s_[pb + 3]); \
        unsigned b1 = pkbf16(s_[pb + 6], s_[pb + 7]); \
        asm("v_permlane32_swap_b32 %0, %1" : "+v"(b0), "+v"(a0)); \
        asm("v_permlane32_swap_b32 %0, %1" : "+v"(b1), "+v"(a1)); \
        union { unsigned u[4]; bf16x8 v8; } bw; \
        bw.u[0] = a0; bw.u[1] = a1; bw.u[2] = b0; bw.u[3] = b1; \
        const int ksa = (KSA0) + h16; \
        int cb = (ksa * 32 + hi * 16) ^ swr; \
        __builtin_amdgcn_s_setprio(1); \
        bf16x8 va0 = *(const bf16x8*)(Vc + ln * 64 + (cb >> 1)); \
        bf16x8 va1 = *(const bf16x8*)(Vc + (ln + 32) * 64 + (cb >> 1)); \
        oT0 = __builtin_amdgcn_mfma_f32_32x32x16_bf16(va0, bw.v8, oT0, 0, 0, 0); \
        oT1 = __builtin_amdgcn_mfma_f32_32x32x16_bf16(va1, bw.v8, oT1, 0, 0, 0); \
        __builtin_amdgcn_s_setprio(0); \
    } \
} while (0)

    for (int t = 0; t < 32; ++t) {
        const int kb_ = t % 3, vb_ = t & 1;
        if (t < 31) STAGE_V(t + 1, (t + 1) & 1);
        if (t < 30) STAGE_K(t + 2, (t + 2) % 3);
        const __bf16* Kc = (const __bf16*)(smb + kb_ * 8192);
        const __bf16* Vc = (const __bf16*)(smb + 24576 + vb_ * 8192);

        DO_STACK(0, 0);    // keys 0..31  -> PV k-slots 0,1
        DO_STACK(32, 2);   // keys 32..63 -> PV k-slots 2,3

        if (t < 30)       BARRIER_VM1();   // K(t+2) in flight; rest drained
        else if (t == 30) BARRIER_VM0();
        else              BARRIER_ONLY();
    }
#undef DO_STACK
#undef STAGE_K
#undef STAGE_V

    float ls = (h < 8) ? oT1[7] : oT1[6];
    float lsp = __shfl_xor(ls, 32);
    float rl = 1.f / (hi ? lsp : ls);

    const int qr = lane & 31, ch = lane >> 5;
#pragma unroll
    for (int r = 0; r < 16; ++r) {
        int d0 = (r & 3) + 8 * (r >> 2) + 4 * hi;
        sm.Olds[wave][ln][d0] = oT0[r] * rl;
    }
    __syncthreads();
    {
        const float* row = &sm.Olds[wave][qr][ch * 16];
        __bf16* dst = attnc + ((size_t)b * SEQ + q0 + qr) * DM + off + ch * 16;
#pragma unroll
        for (int j = 0; j < 16; ++j) dst[j] = (__bf16)row[j];
    }
    __syncthreads();
#pragma unroll
    for (int r = 0; r < 16; ++r) {
        int d0 = (r & 3) + 8 * (r >> 2) + 4 * hi;
        sm.Olds[wave][ln][d0] = oT1[r] * rl;
    }
    __syncthreads();
    {
        const float* row = &sm.Olds[wave][qr][ch * 16];
        __bf16* dst = attnc + ((size_t)b * SEQ + q0 + qr) * DM + off + 32 + ch * 16;
        int lim = hd - 32 - ch * 16;
#pragma unroll
        for (int j = 0; j < 16; ++j)
            if (j < lim) dst[j] = (__bf16)row[j];
    }
}

// ---------------------------------------------------------------------------
extern "C" void kernel_launch(void* const* d_in, const int* in_sizes, int n_in,
                              void* d_out, int out_size, void* d_ws, size_t ws_size,
                              hipStream_t stream)
{
    const float* x   = (const float*)d_in[0];
    const float* Wq  = (const float*)d_in[1];
    const float* Wk  = (const float*)d_in[2];
    const float* Wv  = (const float*)d_in[3];
    const float* g1  = (const float*)d_in[4];
    const float* b1  = (const float*)d_in[5];
    const float* g2  = (const float*)d_in[6];
    const float* b2  = (const float*)d_in[7];
    const float* Wf1 = (const float*)d_in[8];
    const float* bf1 = (const float*)d_in[9];
    const float* Wf2 = (const float*)d_in[10];
    const float* bf2 = (const float*)d_in[11];
    float* out = (float*)d_out;

    const size_t MB = 1024 * 1024;
    if (ws_size < 208 * MB) return;
    char* ws = (char*)d_ws;
    __bf16* Wts  = (__bf16*)(ws);                  // 5 x 0.5MB contiguous
    __bf16* Wf1t = Wts + 3 * DM * DM;
    __bf16* Wf2t = Wts + 4 * DM * DM;
    __bf16* normed_bf = (__bf16*)(ws + 4 * MB);    // 32MB (r' order), attnc alias
    __bf16* qb = (__bf16*)(ws + 36 * MB);          // 48MB
    __bf16* kb = (__bf16*)(ws + 84 * MB);          // 48MB (= qb + SLAB_ELEMS)
    __bf16* vb = (__bf16*)(ws + 132 * MB);         // 48MB (= qb + 2*SLAB_ELEMS)
    __bf16* attnc = normed_bf;
    __bf16* attn_out_bf = (__bf16*)(ws + 100 * MB);// 32MB (r' order)
    __bf16* h1          = (__bf16*)(ws + 132 * MB);// 32MB (r' order, vb dead)

    hipFuncSetAttribute((const void*)gemm256_kernel,
                        hipFuncAttributeMaxDynamicSharedMemorySize, 131072);

    dim3 gg(2, 128);
    dim3 gqkv(6, 128);   // x = z*2+n: A-panel shared by 6 adjacent blocks

    prep_kernel<<<15040, 256, 0, stream>>>(Wq, Wk, Wv, Wf1, Wf2, Wts, qb, vb,
                                           x, g1, b1, normed_bf);
    gemm256_kernel<<<gqkv, 512, 131072, stream>>>(normed_bf, Wts, nullptr, nullptr, qb, -1, 0);
    attn_mfma_kernel<<<BATCH * 12 * (SEQ / 256), 512, 0, stream>>>(qb, kb, vb, attnc);
    ln2_kernel<<<M_ROWS / 4, 256, 0, stream>>>(attnc, x, g2, b2, attn_out_bf);
    gemm256_kernel<<<gg, 512, 131072, stream>>>(attn_out_bf, Wf1t, bf1, nullptr, h1, 4, 1);
    gemm256_kernel<<<gg, 512, 131072, stream>>>(h1, Wf2t, bf2, attn_out_bf, out, 5, 0);
}

// Round 20
// 482.905 us; speedup vs baseline: 1.0444x; 1.0444x over previous
//
#include <hip/hip_runtime.h>
#include <hip/hip_bf16.h>

// ---------------------------------------------------------------------------
// Transformer block. Token rows permuted to r' = b*2048+s after LN1.
// 256x256 8-phase deep-pipelined bf16 MFMA GEMMs + bf16 32x32 swapped-QK^T
// flash attn (8-wave blocks, staged K/V, counted-vmcnt). prep kernel:
// LDS-tile coalesced weight transpose + q pad-zero + v ones + LN1.
// Heads: 8 x 43 + 4 x 42, padded to 64 dims for MFMA.
// ---------------------------------------------------------------------------

#define M_ROWS 32768
#define DM 512
#define SEQ 2048
#define BATCH 16
#define SLAB_ELEMS (24u * 1024u * 1024u)   // 48MB / 2B per QKV slab

typedef __bf16 bf16x8 __attribute__((ext_vector_type(8)));
typedef float f32x4 __attribute__((ext_vector_type(4)));
typedef float f32x16 __attribute__((ext_vector_type(16)));

#define EXP2F(x) __builtin_amdgcn_exp2f(x)

typedef __attribute__((address_space(3))) unsigned lds_u32;
typedef __attribute__((address_space(1))) unsigned glb_u32;
#define GL2LDS(src, dst) __builtin_amdgcn_global_load_lds( \
    (const glb_u32*)(const void*)(src), (lds_u32*)(void*)(dst), 16, 0, 0)

#define BARRIER_VM4() asm volatile("s_waitcnt vmcnt(4)\ns_barrier" ::: "memory")
#define BARRIER_VM1() asm volatile("s_waitcnt vmcnt(1)\ns_barrier" ::: "memory")
#define BARRIER_VM0() asm volatile("s_waitcnt vmcnt(0)\ns_barrier" ::: "memory")
#define BARRIER_ONLY() asm volatile("s_barrier" ::: "memory")

#define MFMA16(a, b, c) __builtin_amdgcn_mfma_f32_16x16x32_bf16(a, b, c, 0, 0, 0)

__device__ inline unsigned pkbf16(float a, float b) {
    unsigned r;
    asm("v_cvt_pk_bf16_f32 %0, %1, %2" : "=v"(r) : "v"(a), "v"(b));
    return r;
}

// ---------------- fused prep --------------------------------------------
// blocks [0,320):        Wt via 64x64 LDS-tile transpose (coalesced both ways)
// blocks [320,1856):     q pad-zero: one 16B store per row (d 40..47)
// blocks [1856,2048):    v^T ones-row at d=hd
// blocks [2048,10240):   LN1: x (r order) -> normed bf16 (r' order)
__global__ __launch_bounds__(256) void prep_kernel(
    const float* __restrict__ Wq, const float* __restrict__ Wk,
    const float* __restrict__ Wv, const float* __restrict__ Wf1,
    const float* __restrict__ Wf2, __bf16* __restrict__ Wts,
    __bf16* __restrict__ q, __bf16* __restrict__ v,
    const float* __restrict__ x, const float* __restrict__ g1,
    const float* __restrict__ b1, __bf16* __restrict__ normed)
{
    __shared__ float tile[64 * 65];
    int blk = blockIdx.x;
    int tid = threadIdx.x;
    if (blk < 320) {
        int g = blk >> 6, t = blk & 63;
        const float* W = (g == 0) ? Wq : (g == 1) ? Wk : (g == 2) ? Wv
                        : (g == 3) ? Wf1 : Wf2;
        __bf16* Wt = Wts + (size_t)g * (DM * DM);
        int kt = (t >> 3) * 64, nt = (t & 7) * 64;
        // coalesced read: rows k, 64 floats each
#pragma unroll
        for (int i = 0; i < 4; ++i) {
            int kl = (tid >> 4) + i * 16;
            int c  = (tid & 15) * 4;
            float4 f4 = *(const float4*)(W + (size_t)(kt + kl) * DM + nt + c);
            tile[kl * 65 + c + 0] = f4.x;
            tile[kl * 65 + c + 1] = f4.y;
            tile[kl * 65 + c + 2] = f4.z;
            tile[kl * 65 + c + 3] = f4.w;
        }
        __syncthreads();
        // coalesced transposed write: row n, 16B chunks of k
#pragma unroll
        for (int i = 0; i < 2; ++i) {
            int nl = (tid >> 3) + i * 32;
            int kl = (tid & 7) * 8;
            union { __bf16 h[8]; bf16x8 v8; } o;
#pragma unroll
            for (int j = 0; j < 8; ++j)
                o.h[j] = (__bf16)tile[(kl + j) * 65 + nl];
            *(bf16x8*)(Wt + (size_t)(nt + nl) * DM + kt + kl) = o.v8;
        }
    } else if (blk < 1856) {
        int row = (blk - 320) * 256 + tid;   // 0..393215
        union { __bf16 h[8]; bf16x8 v8; } z;
#pragma unroll
        for (int j = 0; j < 8; ++j) z.h[j] = (__bf16)0.f;
        *(bf16x8*)(q + (size_t)row * 64 + 40) = z.v8;
    } else if (blk < 2048) {
        int i = (blk - 1856) * 256 + tid;     // 0..49151
        int bh = i >> 8, s8 = i & 255;
        int hd = ((bh % 12) < 8) ? 43 : 42;
        union { __bf16 h[8]; bf16x8 v8; } o;
#pragma unroll
        for (int j = 0; j < 8; ++j) o.h[j] = (__bf16)1.0f;
        *(bf16x8*)(v + ((size_t)bh * 64 + hd) * SEQ + s8 * 8) = o.v8;
    } else {
        int wid  = (int)(((blk - 2048) * 256 + tid) >> 6);   // r'
        int lane = tid & 63;
        int bb = wid >> 11, ss = wid & 2047;
        const float* xrow = x + ((size_t)ss * 16 + bb) * DM;
        float vv[8];
        *(float4*)&vv[0] = *(const float4*)(xrow + lane * 8);
        *(float4*)&vv[4] = *(const float4*)(xrow + lane * 8 + 4);
        float s = 0.f, sq = 0.f;
#pragma unroll
        for (int j = 0; j < 8; ++j) { s += vv[j]; sq = fmaf(vv[j], vv[j], sq); }
#pragma unroll
        for (int i = 1; i < 64; i <<= 1) { s += __shfl_xor(s, i); sq += __shfl_xor(sq, i); }
        float mu   = s * (1.0f / 512.0f);
        float var  = sq * (1.0f / 512.0f) - mu * mu;
        float rstd = rsqrtf(var + 1e-5f);
        union { __bf16 h[8]; bf16x8 v8; } o;
#pragma unroll
        for (int j = 0; j < 8; ++j)
            o.h[j] = (__bf16)((vv[j] - mu) * rstd * g1[lane * 8 + j] + b1[lane * 8 + j]);
        *(bf16x8*)(normed + (size_t)wid * DM + lane * 8) = o.v8;
    }
}

// ---------------- LN2: attnc (r') + x resid (r) -> bf16 out (r') -----------
__global__ __launch_bounds__(256) void ln2_kernel(
    const __bf16* __restrict__ in, const float* __restrict__ res,
    const float* __restrict__ g, const float* __restrict__ b,
    __bf16* __restrict__ outb)
{
    int wid  = (int)((blockIdx.x * 256 + threadIdx.x) >> 6);   // r'
    int lane = threadIdx.x & 63;
    int bb = wid >> 11, ss = wid & 2047;
    union { __bf16 h[8]; bf16x8 v8; } iv;
    iv.v8 = *(const bf16x8*)(in + (size_t)wid * DM + lane * 8);
    const float* rrow = res + ((size_t)ss * 16 + bb) * DM;
    float v[8];
    float4 r0 = *(const float4*)(rrow + lane * 8);
    float4 r1 = *(const float4*)(rrow + lane * 8 + 4);
    v[0] = (float)iv.h[0] + r0.x; v[1] = (float)iv.h[1] + r0.y;
    v[2] = (float)iv.h[2] + r0.z; v[3] = (float)iv.h[3] + r0.w;
    v[4] = (float)iv.h[4] + r1.x; v[5] = (float)iv.h[5] + r1.y;
    v[6] = (float)iv.h[6] + r1.z; v[7] = (float)iv.h[7] + r1.w;
    float s = 0.f, sq = 0.f;
#pragma unroll
    for (int j = 0; j < 8; ++j) { s += v[j]; sq = fmaf(v[j], v[j], sq); }
#pragma unroll
    for (int i = 1; i < 64; i <<= 1) { s += __shfl_xor(s, i); sq += __shfl_xor(sq, i); }
    float mu   = s * (1.0f / 512.0f);
    float var  = sq * (1.0f / 512.0f) - mu * mu;
    float rstd = rsqrtf(var + 1e-5f);
    union { __bf16 h[8]; bf16x8 v8; } ob;
#pragma unroll
    for (int j = 0; j < 8; ++j)
        ob.h[j] = (__bf16)((v[j] - mu) * rstd * g[lane * 8 + j] + b[lane * 8 + j]);
    *(bf16x8*)(outb + (size_t)wid * DM + lane * 8) = ob.v8;
}

// ---------------- 256x256 8-phase bf16 MFMA GEMM (R18 config) --------------
__global__ __launch_bounds__(512, 2) void gemm256_kernel(
    const __bf16* __restrict__ A, const __bf16* __restrict__ Wt,
    const float* __restrict__ bias, const __bf16* __restrict__ residb,
    void* __restrict__ Cout, int mode, int do_relu)
{
    extern __shared__ char lds[];   // 131072 B
    const int tid  = threadIdx.x;
    const int lane = tid & 63, wave = tid >> 6;
    const int wm = wave >> 2, wn = wave & 3;
    const int m0 = blockIdx.y * 256, n0 = blockIdx.x * 256;
    if (mode == -1) {
        mode = 1 + blockIdx.z;
        Wt += (size_t)blockIdx.z * DM * DM;
        Cout = (void*)((__bf16*)Cout + (size_t)blockIdx.z * SLAB_ELEMS);
    }

    const int c0 = tid >> 4, r0 = tid & 15;
    const int rowoff = (c0 >> 2) * 16 + r0;
    const int kcol   = (c0 & 3) * 8;
    const __bf16* aS0 = A  + (size_t)(m0 + rowoff) * DM + kcol;
    const __bf16* aS1 = aS0 + (size_t)128 * DM;
    const __bf16* bS0 = Wt + (size_t)(n0 + rowoff) * DM + kcol;
    const __bf16* bS1 = bS0 + (size_t)128 * DM;

#define STG(tile, hh, buf) do { \
    const int kk_ = (tile) * 64 + ((hh) >> 1) * 32; \
    char* d_ = lds + (buf) * 65536 + ((hh) & 1) * 32768 + ((hh) >> 1) * 16384 + tid * 16; \
    const __bf16* sA_ = ((hh) & 1) ? bS0 : aS0; \
    const __bf16* sB_ = ((hh) & 1) ? bS1 : aS1; \
    GL2LDS(sA_ + kk_, d_); \
    GL2LDS(sB_ + kk_, d_ + 8192); \
} while (0)

    const int aRd = wm * 8192 + (lane >> 4) * 256 + (lane & 15) * 16;
    const int bRd = 32768 + wn * 4096 + (lane >> 4) * 256 + (lane & 15) * 16;

    f32x4 acc[8][4];
#pragma unroll
    for (int m = 0; m < 8; ++m)
#pragma unroll
        for (int n = 0; n < 4; ++n) acc[m][n] = f32x4{0.f, 0.f, 0.f, 0.f};

    STG(0, 0, 0); STG(0, 1, 0); STG(0, 2, 0); STG(0, 3, 0);
    BARRIER_VM4();

    bf16x8 bq0, bq1, bq2, bq3;

#define DO_PHASE(PH) do { \
    constexpr int buf_ = (PH) >> 2, kh_ = ((PH) >> 1) & 1, qm_ = (PH) & 1; \
    if constexpr ((PH) == 0) { if (it != 0) BARRIER_VM4(); } \
    else if constexpr (((PH) & 1) == 0) { \
        if (it == 3 && (PH) >= 4) BARRIER_VM0(); else BARRIER_VM4(); \
    } \
    char* base_ = lds + buf_ * 65536 + kh_ * 16384; \
    bf16x8 af0 = *(const bf16x8*)(base_ + aRd + (qm_ * 4 + 0) * 1024); \
    bf16x8 af1 = *(const bf16x8*)(base_ + aRd + (qm_ * 4 + 1) * 1024); \
    bf16x8 af2 = *(const bf16x8*)(base_ + aRd + (qm_ * 4 + 2) * 1024); \
    bf16x8 af3 = *(const bf16x8*)(base_ + aRd + (qm_ * 4 + 3) * 1024); \
    if constexpr (qm_ == 0) { \
        bq0 = *(const bf16x8*)(base_ + bRd + 0 * 1024); \
        bq1 = *(const bf16x8*)(base_ + bRd + 1 * 1024); \
        bq2 = *(const bf16x8*)(base_ + bRd + 2 * 1024); \
        bq3 = *(const bf16x8*)(base_ + bRd + 3 * 1024); \
    } \
    if constexpr ((PH) < 4) { STG(2 * it + 1, (PH), 1); } \
    else { if (it < 3) STG(2 * it + 2, (PH) - 4, 0); } \
    __builtin_amdgcn_s_setprio(1); \
    acc[qm_ * 4 + 0][0] = MFMA16(af0, bq0, acc[qm_ * 4 + 0][0]); \
    acc[qm_ * 4 + 0][1] = MFMA16(af0, bq1, acc[qm_ * 4 + 0][1]); \
    acc[qm_ * 4 + 0][2] = MFMA16(af0, bq2, acc[qm_ * 4 + 0][2]); \
    acc[qm_ * 4 + 0][3] = MFMA16(af0, bq3, acc[qm_ * 4 + 0][3]); \
    acc[qm_ * 4 + 1][0] = MFMA16(af1, bq0, acc[qm_ * 4 + 1][0]); \
    acc[qm_ * 4 + 1][1] = MFMA16(af1, bq1, acc[qm_ * 4 + 1][1]); \
    acc[qm_ * 4 + 1][2] = MFMA16(af1, bq2, acc[qm_ * 4 + 1][2]); \
    acc[qm_ * 4 + 1][3] = MFMA16(af1, bq3, acc[qm_ * 4 + 1][3]); \
    acc[qm_ * 4 + 2][0] = MFMA16(af2, bq0, acc[qm_ * 4 + 2][0]); \
    acc[qm_ * 4 + 2][1] = MFMA16(af2, bq1, acc[qm_ * 4 + 2][1]); \
    acc[qm_ * 4 + 2][2] = MFMA16(af2, bq2, acc[qm_ * 4 + 2][2]); \
    acc[qm_ * 4 + 2][3] = MFMA16(af2, bq3, acc[qm_ * 4 + 2][3]); \
    acc[qm_ * 4 + 3][0] = MFMA16(af3, bq0, acc[qm_ * 4 + 3][0]); \
    acc[qm_ * 4 + 3][1] = MFMA16(af3, bq1, acc[qm_ * 4 + 3][1]); \
    acc[qm_ * 4 + 3][2] = MFMA16(af3, bq2, acc[qm_ * 4 + 3][2]); \
    acc[qm_ * 4 + 3][3] = MFMA16(af3, bq3, acc[qm_ * 4 + 3][3]); \
    __builtin_amdgcn_s_setprio(0); \
} while (0)

    for (int it = 0; it < 4; ++it) {
        DO_PHASE(0); DO_PHASE(1); DO_PHASE(2); DO_PHASE(3);
        DO_PHASE(4); DO_PHASE(5); DO_PHASE(6); DO_PHASE(7);
    }
#undef DO_PHASE
#undef STG

#pragma unroll
    for (int m = 0; m < 8; ++m) {
#pragma unroll
        for (int n = 0; n < 4; ++n) {
            int col = n0 + wn * 64 + n * 16 + (lane & 15);
            int h = 0, d = 0;
            float sc = 1.f;
            if (mode >= 1 && mode <= 3) {
                if (col < 344) { h = col / 43; d = col - 43 * h; }
                else { int nn = col - 344; h = 8 + nn / 42; d = nn - 42 * (nn / 42); }
                if (mode == 1) sc = (h < 8) ? 0.22000894f : 0.22261268f;
            }
#pragma unroll
            for (int reg = 0; reg < 4; ++reg) {
                int row = m0 + wm * 128 + m * 16 + (lane >> 4) * 4 + reg;
                int b_ = row >> 11, s_ = row & 2047;
                float vv = acc[m][n][reg];
                if (bias) vv += bias[col];
                if (do_relu) vv = fmaxf(vv, 0.f);
                if (mode == 5) {
                    vv += (float)residb[(size_t)row * DM + col];
                    ((float*)Cout)[((size_t)s_ * 16 + b_) * DM + col] = vv;
                } else if (mode == 4) {
                    ((__bf16*)Cout)[(size_t)row * DM + col] = (__bf16)vv;
                } else {
                    if (mode == 1)
                        ((__bf16*)Cout)[(((size_t)b_ * 12 + h) * SEQ + s_) * 64 + d] = (__bf16)(vv * sc);
                    else if (mode == 2)
                        ((__bf16*)Cout)[(((size_t)b_ * 12 + h) * SEQ + s_) * 64 + d] = (__bf16)vv;
                    else
                        ((__bf16*)Cout)[(((size_t)b_ * 12 + h) * 64 + d) * SEQ + s_] = (__bf16)vv;
                }
            }
        }
    }
}

// ---------------- MFMA flash attention (R19, frozen) -----------------------
__global__ __launch_bounds__(512, 5) void attn_mfma_kernel(
    const __bf16* __restrict__ q, const __bf16* __restrict__ k,
    const __bf16* __restrict__ v, __bf16* __restrict__ attnc)
{
    __shared__ union {
        struct { __bf16 K[3][4096]; __bf16 V[2][4096]; } s;   // 40 KB
        float Olds[8][32][33];                                 // 33.8 KB
    } sm;
    char* smb = (char*)&sm;

    const int tid  = threadIdx.x;
    const int wave = tid >> 6, lane = tid & 63;
    const int ln = lane & 31, hi = lane >> 5;

    int sw = (blockIdx.x & 7) * 192 + (blockIdx.x >> 3);
    int qc = sw & 7;
    int h  = (sw >> 3) % 12;
    int b  = sw / 96;
    int hd  = (h < 8) ? 43 : 42;
    int off = (h < 8) ? 43 * h : 42 * h + 8;

    const __bf16* Qbh = q + ((size_t)b * 12 + h) * SEQ * 64;
    const char* Kbase = (const char*)(k + ((size_t)b * 12 + h) * SEQ * 64);
    const char* Vbase = (const char*)(v + ((size_t)b * 12 + h) * 64 * SEQ);

    int q0 = qc * 256 + wave * 32;

    bf16x8 qf[3];
#pragma unroll
    for (int ks = 0; ks < 3; ++ks)
        qf[ks] = *(const bf16x8*)(Qbh + (size_t)(q0 + ln) * 64 + ks * 16 + hi * 8);

    const int rc = tid >> 3;
    const int ob = (tid & 7) << 4;
    const int sb = ob ^ ((rc & 7) << 4);

#define STAGE_K(t, buf) \
    GL2LDS(Kbase + (size_t)(t) * 8192 + rc * 128 + sb, smb + (buf) * 8192 + tid * 16)
#define STAGE_V(t, buf) \
    GL2LDS(Vbase + (size_t)rc * 4096 + (t) * 128 + sb, smb + 24576 + (buf) * 8192 + tid * 16)

    f32x16 oT0, oT1, z16;
#pragma unroll
    for (int i = 0; i < 16; ++i) { oT0[i] = 0.f; oT1[i] = 0.f; z16[i] = 0.f; }

    const int swr = (ln & 7) << 4;

    STAGE_K(0, 0);
    STAGE_V(0, 0);
    STAGE_K(1, 1);
    BARRIER_VM1();

#define DO_STACK(KROW, KSA0) do { \
    f32x16 s_; \
    __builtin_amdgcn_s_setprio(1); \
    { \
        int cb = (hi * 16) ^ swr; \
        bf16x8 ka = *(const bf16x8*)(Kc + (size_t)((KROW) + ln) * 64 + (cb >> 1)); \
        s_ = __builtin_amdgcn_mfma_f32_32x32x16_bf16(ka, qf[0], z16, 0, 0, 0); \
    } \
    { \
        int cb = (32 + hi * 16) ^ swr; \
        bf16x8 ka = *(const bf16x8*)(Kc + (size_t)((KROW) + ln) * 64 + (cb >> 1)); \
        s_ = __builtin_amdgcn_mfma_f32_32x32x16_bf16(ka, qf[1], s_, 0, 0, 0); \
    } \
    { \
        int cb = (64 + hi * 16) ^ swr; \
        bf16x8 ka = *(const bf16x8*)(Kc + (size_t)((KROW) + ln) * 64 + (cb >> 1)); \
        s_ = __builtin_amdgcn_mfma_f32_32x32x16_bf16(ka, qf[2], s_, 0, 0, 0); \
    } \
    __builtin_amdgcn_s_setprio(0); \
    _Pragma("unroll") \
    for (int i = 0; i < 16; ++i) s_[i] = EXP2F(s_[i]); \
    _Pragma("unroll") \
    for (int h16 = 0; h16 < 2; ++h16) { \
        const int pb = h16 * 8; \
        unsigned a0 = pkbf16(s_[pb + 0], s_[pb + 1]); \
        unsigned b0 = pkbf16(s_[pb + 4], s_[pb + 5]); \
        unsigned a1 = pkbf16(s_[pb + 2], s_[pb + 3]); \
        unsigned b1 = pkbf16(s_[pb + 6], s_[pb + 7]); \
        asm("v_permlane32_swap_b32 %0, %1" : "+v"(b0), "+v"(a0)); \
        asm("v_permlane32_swap_b32 %0, %1" : "+v"(b1), "+v"(a1)); \
        union { unsigned u[4]; bf16x8 v8; } bw; \
        bw.u[0] = a0; bw.u[1] = a1; bw.u[2] = b0; bw.u[3] = b1; \
        const int ksa = (KSA0) + h16; \
        int cb = (ksa * 32 + hi * 16) ^ swr; \
        __builtin_amdgcn_s_setprio(1); \
        bf16x8 va0 = *(const bf16x8*)(Vc + ln * 64 + (cb >> 1)); \
        bf16x8 va1 = *(const bf16x8*)(Vc + (ln + 32) * 64 + (cb >> 1)); \
        oT0 = __builtin_amdgcn_mfma_f32_32x32x16_bf16(va0, bw.v8, oT0, 0, 0, 0); \
        oT1 = __builtin_amdgcn_mfma_f32_32x32x16_bf16(va1, bw.v8, oT1, 0, 0, 0); \
        __builtin_amdgcn_s_setprio(0); \
    } \
} while (0)

    for (int t = 0; t < 32; ++t) {
        const int kb_ = t % 3, vb_ = t & 1;
        if (t < 31) STAGE_V(t + 1, (t + 1) & 1);
        if (t < 30) STAGE_K(t + 2, (t + 2) % 3);
        const __bf16* Kc = (const __bf16*)(smb + kb_ * 8192);
        const __bf16* Vc = (const __bf16*)(smb + 24576 + vb_ * 8192);

        DO_STACK(0, 0);
        DO_STACK(32, 2);

        if (t < 30)       BARRIER_VM1();
        else if (t == 30) BARRIER_VM0();
        else              BARRIER_ONLY();
    }
#undef DO_STACK
#undef STAGE_K
#undef STAGE_V

    float ls = (h < 8) ? oT1[7] : oT1[6];
    float lsp = __shfl_xor(ls, 32);
    float rl = 1.f / (hi ? lsp : ls);

    const int qr = lane & 31, ch = lane >> 5;
#pragma unroll
    for (int r = 0; r < 16; ++r) {
        int d0 = (r & 3) + 8 * (r >> 2) + 4 * hi;
        sm.Olds[wave][ln][d0] = oT0[r] * rl;
    }
    __syncthreads();
    {
        const float* row = &sm.Olds[wave][qr][ch * 16];
        __bf16* dst = attnc + ((size_t)b * SEQ + q0 + qr) * DM + off + ch * 16;
#pragma unroll
        for (int j = 0; j < 16; ++j) dst[j] = (__bf16)row[j];
    }
    __syncthreads();
#pragma unroll
    for (int r = 0; r < 16; ++r) {
        int d0 = (r & 3) + 8 * (r >> 2) + 4 * hi;
        sm.Olds[wave][ln][d0] = oT1[r] * rl;
    }
    __syncthreads();
    {
        const float* row = &sm.Olds[wave][qr][ch * 16];
        __bf16* dst = attnc + ((size_t)b * SEQ + q0 + qr) * DM + off + 32 + ch * 16;
        int lim = hd - 32 - ch * 16;
#pragma unroll
        for (int j = 0; j < 16; ++j)
            if (j < lim) dst[j] = (__bf16)row[j];
    }
}

// ---------------------------------------------------------------------------
extern "C" void kernel_launch(void* const* d_in, const int* in_sizes, int n_in,
                              void* d_out, int out_size, void* d_ws, size_t ws_size,
                              hipStream_t stream)
{
    const float* x   = (const float*)d_in[0];
    const float* Wq  = (const float*)d_in[1];
    const float* Wk  = (const float*)d_in[2];
    const float* Wv  = (const float*)d_in[3];
    const float* g1  = (const float*)d_in[4];
    const float* b1  = (const float*)d_in[5];
    const float* g2  = (const float*)d_in[6];
    const float* b2  = (const float*)d_in[7];
    const float* Wf1 = (const float*)d_in[8];
    const float* bf1 = (const float*)d_in[9];
    const float* Wf2 = (const float*)d_in[10];
    const float* bf2 = (const float*)d_in[11];
    float* out = (float*)d_out;

    const size_t MB = 1024 * 1024;
    if (ws_size < 208 * MB) return;
    char* ws = (char*)d_ws;
    __bf16* Wts  = (__bf16*)(ws);                  // 5 x 0.5MB contiguous
    __bf16* Wf1t = Wts + 3 * DM * DM;
    __bf16* Wf2t = Wts + 4 * DM * DM;
    __bf16* normed_bf = (__bf16*)(ws + 4 * MB);    // 32MB (r' order), attnc alias
    __bf16* qb = (__bf16*)(ws + 36 * MB);          // 48MB
    __bf16* kb = (__bf16*)(ws + 84 * MB);          // 48MB (= qb + SLAB_ELEMS)
    __bf16* vb = (__bf16*)(ws + 132 * MB);         // 48MB (= qb + 2*SLAB_ELEMS)
    __bf16* attnc = normed_bf;
    __bf16* attn_out_bf = (__bf16*)(ws + 100 * MB);// 32MB (r' order)
    __bf16* h1          = (__bf16*)(ws + 132 * MB);// 32MB (r' order, vb dead)

    hipFuncSetAttribute((const void*)gemm256_kernel,
                        hipFuncAttributeMaxDynamicSharedMemorySize, 131072);

    dim3 gg(2, 128);
    dim3 gqkv(2, 128, 3);

    prep_kernel<<<10240, 256, 0, stream>>>(Wq, Wk, Wv, Wf1, Wf2, Wts, qb, vb,
                                           x, g1, b1, normed_bf);
    gemm256_kernel<<<gqkv, 512, 131072, stream>>>(normed_bf, Wts, nullptr, nullptr, qb, -1, 0);
    attn_mfma_kernel<<<BATCH * 12 * (SEQ / 256), 512, 0, stream>>>(qb, kb, vb, attnc);
    ln2_kernel<<<M_ROWS / 4, 256, 0, stream>>>(attnc, x, g2, b2, attn_out_bf);
    gemm256_kernel<<<gg, 512, 131072, stream>>>(attn_out_bf, Wf1t, bf1, nullptr, h1, 4, 1);
    gemm256_kernel<<<gg, 512, 131072, stream>>>(h1, Wf2t, bf2, attn_out_bf, out, 5, 0);
}

// Round 21
// 482.196 us; speedup vs baseline: 1.0460x; 1.0015x over previous
//
#include <hip/hip_runtime.h>
#include <hip/hip_bf16.h>

// ---------------------------------------------------------------------------
// Transformer block. Token rows permuted to r' = b*2048+s after LN1.
// 256x256 8-phase deep-pipelined bf16 MFMA GEMMs + bf16 32x32 swapped-QK^T
// flash attn (8-wave blocks; K 4-buf / V 3-buf staged K/V with 2-tile
// prefetch lead, barrier vmcnt(3)). prep: LDS-tile coalesced weight
// transpose + q pad-zero + v ones + LN1.
// Heads: 8 x 43 + 4 x 42, padded to 64 dims for MFMA.
// ---------------------------------------------------------------------------

#define M_ROWS 32768
#define DM 512
#define SEQ 2048
#define BATCH 16
#define SLAB_ELEMS (24u * 1024u * 1024u)   // 48MB / 2B per QKV slab

typedef __bf16 bf16x8 __attribute__((ext_vector_type(8)));
typedef float f32x4 __attribute__((ext_vector_type(4)));
typedef float f32x16 __attribute__((ext_vector_type(16)));

#define EXP2F(x) __builtin_amdgcn_exp2f(x)

typedef __attribute__((address_space(3))) unsigned lds_u32;
typedef __attribute__((address_space(1))) unsigned glb_u32;
#define GL2LDS(src, dst) __builtin_amdgcn_global_load_lds( \
    (const glb_u32*)(const void*)(src), (lds_u32*)(void*)(dst), 16, 0, 0)

#define BARRIER_VM4() asm volatile("s_waitcnt vmcnt(4)\ns_barrier" ::: "memory")
#define BARRIER_VM3() asm volatile("s_waitcnt vmcnt(3)\ns_barrier" ::: "memory")
#define BARRIER_VM2() asm volatile("s_waitcnt vmcnt(2)\ns_barrier" ::: "memory")
#define BARRIER_VM0() asm volatile("s_waitcnt vmcnt(0)\ns_barrier" ::: "memory")
#define BARRIER_ONLY() asm volatile("s_barrier" ::: "memory")

#define MFMA16(a, b, c) __builtin_amdgcn_mfma_f32_16x16x32_bf16(a, b, c, 0, 0, 0)

__device__ inline unsigned pkbf16(float a, float b) {
    unsigned r;
    asm("v_cvt_pk_bf16_f32 %0, %1, %2" : "=v"(r) : "v"(a), "v"(b));
    return r;
}

// ---------------- fused prep --------------------------------------------
// blocks [0,320):        Wt via 64x64 LDS-tile transpose (coalesced both ways)
// blocks [320,1856):     q pad-zero: one 16B store per row (d 40..47)
// blocks [1856,2048):    v^T ones-row at d=hd
// blocks [2048,10240):   LN1: x (r order) -> normed bf16 (r' order)
__global__ __launch_bounds__(256) void prep_kernel(
    const float* __restrict__ Wq, const float* __restrict__ Wk,
    const float* __restrict__ Wv, const float* __restrict__ Wf1,
    const float* __restrict__ Wf2, __bf16* __restrict__ Wts,
    __bf16* __restrict__ q, __bf16* __restrict__ v,
    const float* __restrict__ x, const float* __restrict__ g1,
    const float* __restrict__ b1, __bf16* __restrict__ normed)
{
    __shared__ float tile[64 * 65];
    int blk = blockIdx.x;
    int tid = threadIdx.x;
    if (blk < 320) {
        int g = blk >> 6, t = blk & 63;
        const float* W = (g == 0) ? Wq : (g == 1) ? Wk : (g == 2) ? Wv
                        : (g == 3) ? Wf1 : Wf2;
        __bf16* Wt = Wts + (size_t)g * (DM * DM);
        int kt = (t >> 3) * 64, nt = (t & 7) * 64;
#pragma unroll
        for (int i = 0; i < 4; ++i) {
            int kl = (tid >> 4) + i * 16;
            int c  = (tid & 15) * 4;
            float4 f4 = *(const float4*)(W + (size_t)(kt + kl) * DM + nt + c);
            tile[kl * 65 + c + 0] = f4.x;
            tile[kl * 65 + c + 1] = f4.y;
            tile[kl * 65 + c + 2] = f4.z;
            tile[kl * 65 + c + 3] = f4.w;
        }
        __syncthreads();
#pragma unroll
        for (int i = 0; i < 2; ++i) {
            int nl = (tid >> 3) + i * 32;
            int kl = (tid & 7) * 8;
            union { __bf16 h[8]; bf16x8 v8; } o;
#pragma unroll
            for (int j = 0; j < 8; ++j)
                o.h[j] = (__bf16)tile[(kl + j) * 65 + nl];
            *(bf16x8*)(Wt + (size_t)(nt + nl) * DM + kt + kl) = o.v8;
        }
    } else if (blk < 1856) {
        int row = (blk - 320) * 256 + tid;   // 0..393215
        union { __bf16 h[8]; bf16x8 v8; } z;
#pragma unroll
        for (int j = 0; j < 8; ++j) z.h[j] = (__bf16)0.f;
        *(bf16x8*)(q + (size_t)row * 64 + 40) = z.v8;
    } else if (blk < 2048) {
        int i = (blk - 1856) * 256 + tid;     // 0..49151
        int bh = i >> 8, s8 = i & 255;
        int hd = ((bh % 12) < 8) ? 43 : 42;
        union { __bf16 h[8]; bf16x8 v8; } o;
#pragma unroll
        for (int j = 0; j < 8; ++j) o.h[j] = (__bf16)1.0f;
        *(bf16x8*)(v + ((size_t)bh * 64 + hd) * SEQ + s8 * 8) = o.v8;
    } else {
        int wid  = (int)(((blk - 2048) * 256 + tid) >> 6);   // r'
        int lane = tid & 63;
        int bb = wid >> 11, ss = wid & 2047;
        const float* xrow = x + ((size_t)ss * 16 + bb) * DM;
        float vv[8];
        *(float4*)&vv[0] = *(const float4*)(xrow + lane * 8);
        *(float4*)&vv[4] = *(const float4*)(xrow + lane * 8 + 4);
        float s = 0.f, sq = 0.f;
#pragma unroll
        for (int j = 0; j < 8; ++j) { s += vv[j]; sq = fmaf(vv[j], vv[j], sq); }
#pragma unroll
        for (int i = 1; i < 64; i <<= 1) { s += __shfl_xor(s, i); sq += __shfl_xor(sq, i); }
        float mu   = s * (1.0f / 512.0f);
        float var  = sq * (1.0f / 512.0f) - mu * mu;
        float rstd = rsqrtf(var + 1e-5f);
        union { __bf16 h[8]; bf16x8 v8; } o;
#pragma unroll
        for (int j = 0; j < 8; ++j)
            o.h[j] = (__bf16)((vv[j] - mu) * rstd * g1[lane * 8 + j] + b1[lane * 8 + j]);
        *(bf16x8*)(normed + (size_t)wid * DM + lane * 8) = o.v8;
    }
}

// ---------------- LN2: attnc (r') + x resid (r) -> bf16 out (r') -----------
__global__ __launch_bounds__(256) void ln2_kernel(
    const __bf16* __restrict__ in, const float* __restrict__ res,
    const float* __restrict__ g, const float* __restrict__ b,
    __bf16* __restrict__ outb)
{
    int wid  = (int)((blockIdx.x * 256 + threadIdx.x) >> 6);   // r'
    int lane = threadIdx.x & 63;
    int bb = wid >> 11, ss = wid & 2047;
    union { __bf16 h[8]; bf16x8 v8; } iv;
    iv.v8 = *(const bf16x8*)(in + (size_t)wid * DM + lane * 8);
    const float* rrow = res + ((size_t)ss * 16 + bb) * DM;
    float v[8];
    float4 r0 = *(const float4*)(rrow + lane * 8);
    float4 r1 = *(const float4*)(rrow + lane * 8 + 4);
    v[0] = (float)iv.h[0] + r0.x; v[1] = (float)iv.h[1] + r0.y;
    v[2] = (float)iv.h[2] + r0.z; v[3] = (float)iv.h[3] + r0.w;
    v[4] = (float)iv.h[4] + r1.x; v[5] = (float)iv.h[5] + r1.y;
    v[6] = (float)iv.h[6] + r1.z; v[7] = (float)iv.h[7] + r1.w;
    float s = 0.f, sq = 0.f;
#pragma unroll
    for (int j = 0; j < 8; ++j) { s += v[j]; sq = fmaf(v[j], v[j], sq); }
#pragma unroll
    for (int i = 1; i < 64; i <<= 1) { s += __shfl_xor(s, i); sq += __shfl_xor(sq, i); }
    float mu   = s * (1.0f / 512.0f);
    float var  = sq * (1.0f / 512.0f) - mu * mu;
    float rstd = rsqrtf(var + 1e-5f);
    union { __bf16 h[8]; bf16x8 v8; } ob;
#pragma unroll
    for (int j = 0; j < 8; ++j)
        ob.h[j] = (__bf16)((v[j] - mu) * rstd * g[lane * 8 + j] + b[lane * 8 + j]);
    *(bf16x8*)(outb + (size_t)wid * DM + lane * 8) = ob.v8;
}

// ---------------- 256x256 8-phase bf16 MFMA GEMM (frozen) ------------------
__global__ __launch_bounds__(512, 2) void gemm256_kernel(
    const __bf16* __restrict__ A, const __bf16* __restrict__ Wt,
    const float* __restrict__ bias, const __bf16* __restrict__ residb,
    void* __restrict__ Cout, int mode, int do_relu)
{
    extern __shared__ char lds[];   // 131072 B
    const int tid  = threadIdx.x;
    const int lane = tid & 63, wave = tid >> 6;
    const int wm = wave >> 2, wn = wave & 3;
    const int m0 = blockIdx.y * 256, n0 = blockIdx.x * 256;
    if (mode == -1) {
        mode = 1 + blockIdx.z;
        Wt += (size_t)blockIdx.z * DM * DM;
        Cout = (void*)((__bf16*)Cout + (size_t)blockIdx.z * SLAB_ELEMS);
    }

    const int c0 = tid >> 4, r0 = tid & 15;
    const int rowoff = (c0 >> 2) * 16 + r0;
    const int kcol   = (c0 & 3) * 8;
    const __bf16* aS0 = A  + (size_t)(m0 + rowoff) * DM + kcol;
    const __bf16* aS1 = aS0 + (size_t)128 * DM;
    const __bf16* bS0 = Wt + (size_t)(n0 + rowoff) * DM + kcol;
    const __bf16* bS1 = bS0 + (size_t)128 * DM;

#define STG(tile, hh, buf) do { \
    const int kk_ = (tile) * 64 + ((hh) >> 1) * 32; \
    char* d_ = lds + (buf) * 65536 + ((hh) & 1) * 32768 + ((hh) >> 1) * 16384 + tid * 16; \
    const __bf16* sA_ = ((hh) & 1) ? bS0 : aS0; \
    const __bf16* sB_ = ((hh) & 1) ? bS1 : aS1; \
    GL2LDS(sA_ + kk_, d_); \
    GL2LDS(sB_ + kk_, d_ + 8192); \
} while (0)

    const int aRd = wm * 8192 + (lane >> 4) * 256 + (lane & 15) * 16;
    const int bRd = 32768 + wn * 4096 + (lane >> 4) * 256 + (lane & 15) * 16;

    f32x4 acc[8][4];
#pragma unroll
    for (int m = 0; m < 8; ++m)
#pragma unroll
        for (int n = 0; n < 4; ++n) acc[m][n] = f32x4{0.f, 0.f, 0.f, 0.f};

    STG(0, 0, 0); STG(0, 1, 0); STG(0, 2, 0); STG(0, 3, 0);
    BARRIER_VM4();

    bf16x8 bq0, bq1, bq2, bq3;

#define DO_PHASE(PH) do { \
    constexpr int buf_ = (PH) >> 2, kh_ = ((PH) >> 1) & 1, qm_ = (PH) & 1; \
    if constexpr ((PH) == 0) { if (it != 0) BARRIER_VM4(); } \
    else if constexpr (((PH) & 1) == 0) { \
        if (it == 3 && (PH) >= 4) BARRIER_VM0(); else BARRIER_VM4(); \
    } \
    char* base_ = lds + buf_ * 65536 + kh_ * 16384; \
    bf16x8 af0 = *(const bf16x8*)(base_ + aRd + (qm_ * 4 + 0) * 1024); \
    bf16x8 af1 = *(const bf16x8*)(base_ + aRd + (qm_ * 4 + 1) * 1024); \
    bf16x8 af2 = *(const bf16x8*)(base_ + aRd + (qm_ * 4 + 2) * 1024); \
    bf16x8 af3 = *(const bf16x8*)(base_ + aRd + (qm_ * 4 + 3) * 1024); \
    if constexpr (qm_ == 0) { \
        bq0 = *(const bf16x8*)(base_ + bRd + 0 * 1024); \
        bq1 = *(const bf16x8*)(base_ + bRd + 1 * 1024); \
        bq2 = *(const bf16x8*)(base_ + bRd + 2 * 1024); \
        bq3 = *(const bf16x8*)(base_ + bRd + 3 * 1024); \
    } \
    if constexpr ((PH) < 4) { STG(2 * it + 1, (PH), 1); } \
    else { if (it < 3) STG(2 * it + 2, (PH) - 4, 0); } \
    __builtin_amdgcn_s_setprio(1); \
    acc[qm_ * 4 + 0][0] = MFMA16(af0, bq0, acc[qm_ * 4 + 0][0]); \
    acc[qm_ * 4 + 0][1] = MFMA16(af0, bq1, acc[qm_ * 4 + 0][1]); \
    acc[qm_ * 4 + 0][2] = MFMA16(af0, bq2, acc[qm_ * 4 + 0][2]); \
    acc[qm_ * 4 + 0][3] = MFMA16(af0, bq3, acc[qm_ * 4 + 0][3]); \
    acc[qm_ * 4 + 1][0] = MFMA16(af1, bq0, acc[qm_ * 4 + 1][0]); \
    acc[qm_ * 4 + 1][1] = MFMA16(af1, bq1, acc[qm_ * 4 + 1][1]); \
    acc[qm_ * 4 + 1][2] = MFMA16(af1, bq2, acc[qm_ * 4 + 1][2]); \
    acc[qm_ * 4 + 1][3] = MFMA16(af1, bq3, acc[qm_ * 4 + 1][3]); \
    acc[qm_ * 4 + 2][0] = MFMA16(af2, bq0, acc[qm_ * 4 + 2][0]); \
    acc[qm_ * 4 + 2][1] = MFMA16(af2, bq1, acc[qm_ * 4 + 2][1]); \
    acc[qm_ * 4 + 2][2] = MFMA16(af2, bq2, acc[qm_ * 4 + 2][2]); \
    acc[qm_ * 4 + 2][3] = MFMA16(af2, bq3, acc[qm_ * 4 + 2][3]); \
    acc[qm_ * 4 + 3][0] = MFMA16(af3, bq0, acc[qm_ * 4 + 3][0]); \
    acc[qm_ * 4 + 3][1] = MFMA16(af3, bq1, acc[qm_ * 4 + 3][1]); \
    acc[qm_ * 4 + 3][2] = MFMA16(af3, bq2, acc[qm_ * 4 + 3][2]); \
    acc[qm_ * 4 + 3][3] = MFMA16(af3, bq3, acc[qm_ * 4 + 3][3]); \
    __builtin_amdgcn_s_setprio(0); \
} while (0)

    for (int it = 0; it < 4; ++it) {
        DO_PHASE(0); DO_PHASE(1); DO_PHASE(2); DO_PHASE(3);
        DO_PHASE(4); DO_PHASE(5); DO_PHASE(6); DO_PHASE(7);
    }
#undef DO_PHASE
#undef STG

#pragma unroll
    for (int m = 0; m < 8; ++m) {
#pragma unroll
        for (int n = 0; n < 4; ++n) {
            int col = n0 + wn * 64 + n * 16 + (lane & 15);
            int h = 0, d = 0;
            float sc = 1.f;
            if (mode >= 1 && mode <= 3) {
                if (col < 344) { h = col / 43; d = col - 43 * h; }
                else { int nn = col - 344; h = 8 + nn / 42; d = nn - 42 * (nn / 42); }
                if (mode == 1) sc = (h < 8) ? 0.22000894f : 0.22261268f;
            }
#pragma unroll
            for (int reg = 0; reg < 4; ++reg) {
                int row = m0 + wm * 128 + m * 16 + (lane >> 4) * 4 + reg;
                int b_ = row >> 11, s_ = row & 2047;
                float vv = acc[m][n][reg];
                if (bias) vv += bias[col];
                if (do_relu) vv = fmaxf(vv, 0.f);
                if (mode == 5) {
                    vv += (float)residb[(size_t)row * DM + col];
                    ((float*)Cout)[((size_t)s_ * 16 + b_) * DM + col] = vv;
                } else if (mode == 4) {
                    ((__bf16*)Cout)[(size_t)row * DM + col] = (__bf16)vv;
                } else {
                    if (mode == 1)
                        ((__bf16*)Cout)[(((size_t)b_ * 12 + h) * SEQ + s_) * 64 + d] = (__bf16)(vv * sc);
                    else if (mode == 2)
                        ((__bf16*)Cout)[(((size_t)b_ * 12 + h) * SEQ + s_) * 64 + d] = (__bf16)vv;
                    else
                        ((__bf16*)Cout)[(((size_t)b_ * 12 + h) * 64 + d) * SEQ + s_] = (__bf16)vv;
                }
            }
        }
    }
}

// ---------------- MFMA flash attention: K 4-buf / V 3-buf, vmcnt(3) --------
// 512 threads = 8 waves x 32 queries. Stage V(t+2), K(t+3) each iter:
// every consumed buffer has >=2-tile prefetch lead. LDS 56KB (2 blocks/CU,
// same as the 16-wave register cap -> no occupancy cost).
__global__ __launch_bounds__(512, 5) void attn_mfma_kernel(
    const __bf16* __restrict__ q, const __bf16* __restrict__ k,
    const __bf16* __restrict__ v, __bf16* __restrict__ attnc)
{
    __shared__ union {
        struct { __bf16 K[4][4096]; __bf16 V[3][4096]; } s;   // 56 KB
        float Olds[8][32][33];                                 // 33.8 KB
    } sm;
    char* smb = (char*)&sm;

    const int tid  = threadIdx.x;
    const int wave = tid >> 6, lane = tid & 63;
    const int ln = lane & 31, hi = lane >> 5;

    int sw = (blockIdx.x & 7) * 192 + (blockIdx.x >> 3);
    int qc = sw & 7;
    int h  = (sw >> 3) % 12;
    int b  = sw / 96;
    int hd  = (h < 8) ? 43 : 42;
    int off = (h < 8) ? 43 * h : 42 * h + 8;

    const __bf16* Qbh = q + ((size_t)b * 12 + h) * SEQ * 64;
    const char* Kbase = (const char*)(k + ((size_t)b * 12 + h) * SEQ * 64);
    const char* Vbase = (const char*)(v + ((size_t)b * 12 + h) * 64 * SEQ);

    int q0 = qc * 256 + wave * 32;

    bf16x8 qf[3];
#pragma unroll
    for (int ks = 0; ks < 3; ++ks)
        qf[ks] = *(const bf16x8*)(Qbh + (size_t)(q0 + ln) * 64 + ks * 16 + hi * 8);

    const int rc = tid >> 3;
    const int ob = (tid & 7) << 4;
    const int sb = ob ^ ((rc & 7) << 4);

#define STAGE_K(t, buf) \
    GL2LDS(Kbase + (size_t)(t) * 8192 + rc * 128 + sb, smb + (buf) * 8192 + tid * 16)
#define STAGE_V(t, buf) \
    GL2LDS(Vbase + (size_t)rc * 4096 + (t) * 128 + sb, smb + 32768 + (buf) * 8192 + tid * 16)

    f32x16 oT0, oT1, z16;
#pragma unroll
    for (int i = 0; i < 16; ++i) { oT0[i] = 0.f; oT1[i] = 0.f; z16[i] = 0.f; }

    const int swr = (ln & 7) << 4;

    // prologue: K0 V0 K1 V1 K2 in flight; need K0,V0 -> vmcnt(3)
    STAGE_K(0, 0);
    STAGE_V(0, 0);
    STAGE_K(1, 1);
    STAGE_V(1, 1);
    STAGE_K(2, 2);
    BARRIER_VM3();

#define DO_STACK(KROW, KSA0) do { \
    f32x16 s_; \
    __builtin_amdgcn_s_setprio(1); \
    { \
        int cb = (hi * 16) ^ swr; \
        bf16x8 ka = *(const bf16x8*)(Kc + (size_t)((KROW) + ln) * 64 + (cb >> 1)); \
        s_ = __builtin_amdgcn_mfma_f32_32x32x16_bf16(ka, qf[0], z16, 0, 0, 0); \
    } \
    { \
        int cb = (32 + hi * 16) ^ swr; \
        bf16x8 ka = *(const bf16x8*)(Kc + (size_t)((KROW) + ln) * 64 + (cb >> 1)); \
        s_ = __builtin_amdgcn_mfma_f32_32x32x16_bf16(ka, qf[1], s_, 0, 0, 0); \
    } \
    { \
        int cb = (64 + hi * 16) ^ swr; \
        bf16x8 ka = *(const bf16x8*)(Kc + (size_t)((KROW) + ln) * 64 + (cb >> 1)); \
        s_ = __builtin_amdgcn_mfma_f32_32x32x16_bf16(ka, qf[2], s_, 0, 0, 0); \
    } \
    __builtin_amdgcn_s_setprio(0); \
    _Pragma("unroll") \
    for (int i = 0; i < 16; ++i) s_[i] = EXP2F(s_[i]); \
    _Pragma("unroll") \
    for (int h16 = 0; h16 < 2; ++h16) { \
        const int pb = h16 * 8; \
        unsigned a0 = pkbf16(s_[pb + 0], s_[pb + 1]); \
        unsigned b0 = pkbf16(s_[pb + 4], s_[pb + 5]); \
        unsigned a1 = pkbf16(s_[pb + 2], s_[pb + 3]); \
        unsigned b1 = pkbf16(s_[pb + 6], s_[pb + 7]); \
        asm("v_permlane32_swap_b32 %0, %1" : "+v"(b0), "+v"(a0)); \
        asm("v_permlane32_swap_b32 %0, %1" : "+v"(b1), "+v"(a1)); \
        union { unsigned u[4]; bf16x8 v8; } bw; \
        bw.u[0] = a0; bw.u[1] = a1; bw.u[2] = b0; bw.u[3] = b1; \
        const int ksa = (KSA0) + h16; \
        int cb = (ksa * 32 + hi * 16) ^ swr; \
        __builtin_amdgcn_s_setprio(1); \
        bf16x8 va0 = *(const bf16x8*)(Vc + ln * 64 + (cb >> 1)); \
        bf16x8 va1 = *(const bf16x8*)(Vc + (ln + 32) * 64 + (cb >> 1)); \
        oT0 = __builtin_amdgcn_mfma_f32_32x32x16_bf16(va0, bw.v8, oT0, 0, 0, 0); \
        oT1 = __builtin_amdgcn_mfma_f32_32x32x16_bf16(va1, bw.v8, oT1, 0, 0, 0); \
        __builtin_amdgcn_s_setprio(0); \
    } \
} while (0)

    for (int t = 0; t < 32; ++t) {
        const int kb_ = t & 3, vb_ = t % 3;
        if (t < 30) STAGE_V(t + 2, (t + 2) % 3);
        if (t < 29) STAGE_K(t + 3, (t + 3) & 3);
        const __bf16* Kc = (const __bf16*)(smb + kb_ * 8192);
        const __bf16* Vc = (const __bf16*)(smb + 32768 + vb_ * 8192);

        DO_STACK(0, 0);    // keys 0..31  -> PV k-slots 0,1
        DO_STACK(32, 2);   // keys 32..63 -> PV k-slots 2,3

        // queue at barrier: [V(t+1), K(t+2), V(t+2), K(t+3)] -> vmcnt(3)
        if (t < 29)       BARRIER_VM3();
        else if (t == 29) BARRIER_VM2();   // [K(31), V(31)] + drained
        else if (t == 30) BARRIER_VM0();
        else              BARRIER_ONLY();  // epilogue alias handoff
    }
#undef DO_STACK
#undef STAGE_K
#undef STAGE_V

    float ls = (h < 8) ? oT1[7] : oT1[6];
    float lsp = __shfl_xor(ls, 32);
    float rl = 1.f / (hi ? lsp : ls);

    const int qr = lane & 31, ch = lane >> 5;
#pragma unroll
    for (int r = 0; r < 16; ++r) {
        int d0 = (r & 3) + 8 * (r >> 2) + 4 * hi;
        sm.Olds[wave][ln][d0] = oT0[r] * rl;
    }
    __syncthreads();
    {
        const float* row = &sm.Olds[wave][qr][ch * 16];
        __bf16* dst = attnc + ((size_t)b * SEQ + q0 + qr) * DM + off + ch * 16;
#pragma unroll
        for (int j = 0; j < 16; ++j) dst[j] = (__bf16)row[j];
    }
    __syncthreads();
#pragma unroll
    for (int r = 0; r < 16; ++r) {
        int d0 = (r & 3) + 8 * (r >> 2) + 4 * hi;
        sm.Olds[wave][ln][d0] = oT1[r] * rl;
    }
    __syncthreads();
    {
        const float* row = &sm.Olds[wave][qr][ch * 16];
        __bf16* dst = attnc + ((size_t)b * SEQ + q0 + qr) * DM + off + 32 + ch * 16;
        int lim = hd - 32 - ch * 16;
#pragma unroll
        for (int j = 0; j < 16; ++j)
            if (j < lim) dst[j] = (__bf16)row[j];
    }
}

// ---------------------------------------------------------------------------
extern "C" void kernel_launch(void* const* d_in, const int* in_sizes, int n_in,
                              void* d_out, int out_size, void* d_ws, size_t ws_size,
                              hipStream_t stream)
{
    const float* x   = (const float*)d_in[0];
    const float* Wq  = (const float*)d_in[1];
    const float* Wk  = (const float*)d_in[2];
    const float* Wv  = (const float*)d_in[3];
    const float* g1  = (const float*)d_in[4];
    const float* b1  = (const float*)d_in[5];
    const float* g2  = (const float*)d_in[6];
    const float* b2  = (const float*)d_in[7];
    const float* Wf1 = (const float*)d_in[8];
    const float* bf1 = (const float*)d_in[9];
    const float* Wf2 = (const float*)d_in[10];
    const float* bf2 = (const float*)d_in[11];
    float* out = (float*)d_out;

    const size_t MB = 1024 * 1024;
    if (ws_size < 208 * MB) return;
    char* ws = (char*)d_ws;
    __bf16* Wts  = (__bf16*)(ws);                  // 5 x 0.5MB contiguous
    __bf16* Wf1t = Wts + 3 * DM * DM;
    __bf16* Wf2t = Wts + 4 * DM * DM;
    __bf16* normed_bf = (__bf16*)(ws + 4 * MB);    // 32MB (r' order), attnc alias
    __bf16* qb = (__bf16*)(ws + 36 * MB);          // 48MB
    __bf16* kb = (__bf16*)(ws + 84 * MB);          // 48MB (= qb + SLAB_ELEMS)
    __bf16* vb = (__bf16*)(ws + 132 * MB);         // 48MB (= qb + 2*SLAB_ELEMS)
    __bf16* attnc = normed_bf;
    __bf16* attn_out_bf = (__bf16*)(ws + 100 * MB);// 32MB (r' order)
    __bf16* h1          = (__bf16*)(ws + 132 * MB);// 32MB (r' order, vb dead)

    hipFuncSetAttribute((const void*)gemm256_kernel,
                        hipFuncAttributeMaxDynamicSharedMemorySize, 131072);

    dim3 gg(2, 128);
    dim3 gqkv(2, 128, 3);

    prep_kernel<<<10240, 256, 0, stream>>>(Wq, Wk, Wv, Wf1, Wf2, Wts, qb, vb,
                                           x, g1, b1, normed_bf);
    gemm256_kernel<<<gqkv, 512, 131072, stream>>>(normed_bf, Wts, nullptr, nullptr, qb, -1, 0);
    attn_mfma_kernel<<<BATCH * 12 * (SEQ / 256), 512, 0, stream>>>(qb, kb, vb, attnc);
    ln2_kernel<<<M_ROWS / 4, 256, 0, stream>>>(attnc, x, g2, b2, attn_out_bf);
    gemm256_kernel<<<gg, 512, 131072, stream>>>(attn_out_bf, Wf1t, bf1, nullptr, h1, 4, 1);
    gemm256_kernel<<<gg, 512, 131072, stream>>>(h1, Wf2t, bf2, attn_out_bf, out, 5, 0);
}